// Round 14
// baseline (152.764 us; speedup 1.0000x reference)
//
#include <hip/hip_runtime.h>
#include <hip/hip_bf16.h>

typedef __hip_bfloat16 bf16;
typedef __attribute__((ext_vector_type(8))) short short8v;
typedef __attribute__((ext_vector_type(4))) float f32x4;

#define NSLICE 32   // B*S
#define HW     1024 // H*W
#define CDIM   256  // C1 == C2 == C
#define KVT    32   // kv tokens per flash inner tile

// ---------------------------------------------------------------------------
// Kernel 0: W^T prep. W f32 [cin][cout] -> wt bf16 [mat][cout][cin].
// Wq (mat 0) prescaled by 1/16.
// ---------------------------------------------------------------------------
__global__ __launch_bounds__(256)
void wt_prep_kernel(const float* __restrict__ Wq, const float* __restrict__ Wk,
                    const float* __restrict__ Wv, bf16* __restrict__ wt)
{
    const int m = blockIdx.x >> 8;
    const int r = blockIdx.x & 255;
    const int tid = threadIdx.x;
    const float* W = (m == 0) ? Wq : (m == 1) ? Wk : Wv;
    const float sc = (m == 0) ? 0.0625f : 1.0f;
    wt[((size_t)m << 16) + (size_t)tid * 256 + r] = __float2bfloat16(W[r * 256 + tid] * sc);
}

// ---------------------------------------------------------------------------
// Kernel 1a: Q projection (exact round-9 version).
// ---------------------------------------------------------------------------
__global__ __launch_bounds__(256)
void proj_q_kernel(const float* __restrict__ img, const bf16* __restrict__ wt,
                   const float* __restrict__ bq, bf16* __restrict__ qo)
{
    const int bid   = blockIdx.x;
    const int s     = (bid & 7) * 4 + ((bid >> 3) & 3);
    const int tt    = (bid >> 5) & 15;
    const int chalf = bid >> 9;
    const int t0    = tt * 64;

    const int tid  = threadIdx.x;
    const int wave = tid >> 6;
    const int lane = tid & 63;
    const int lo16 = lane & 15;
    const int hi4  = lane >> 4;
    const int cw0  = chalf * 128 + wave * 32;

    __shared__ short Ai[64][40];

    const int so = tid >> 6, st = tid & 63;
    const float* imgS = img + (size_t)s * CDIM * HW + t0;

    f32x4 aq[2][4];
    #pragma unroll
    for (int a = 0; a < 2; ++a)
        #pragma unroll
        for (int b = 0; b < 4; ++b) aq[a][b] = (f32x4){0.f, 0.f, 0.f, 0.f};

    float ri[8];
    #pragma unroll
    for (int j = 0; j < 8; ++j) ri[j] = imgS[(size_t)(so * 8 + j) * HW + st];

    for (int kc = 0; kc < 8; ++kc) {
        __syncthreads();
        {
            short ti[8];
            #pragma unroll
            for (int j = 0; j < 8; ++j) {
                bf16 hb = __float2bfloat16(ri[j]);
                ti[j] = *reinterpret_cast<short*>(&hb);
            }
            *reinterpret_cast<short8v*>(&Ai[st][so * 8]) = *reinterpret_cast<short8v*>(ti);
        }
        __syncthreads();

        if (kc < 7) {
            #pragma unroll
            for (int j = 0; j < 8; ++j)
                ri[j] = imgS[(size_t)((kc + 1) * 32 + so * 8 + j) * HW + st];
        }

        short8v xi[4];
        #pragma unroll
        for (int nf = 0; nf < 4; ++nf)
            xi[nf] = *reinterpret_cast<const short8v*>(&Ai[nf * 16 + lo16][hi4 * 8]);

        const int koff = kc * 32 + hi4 * 8;
        short8v wqf[2];
        #pragma unroll
        for (int mf = 0; mf < 2; ++mf)
            wqf[mf] = *reinterpret_cast<const short8v*>(
                wt + (size_t)(cw0 + mf * 16 + lo16) * 256 + koff);

        #pragma unroll
        for (int mf = 0; mf < 2; ++mf)
            #pragma unroll
            for (int nf = 0; nf < 4; ++nf)
                aq[mf][nf] = __builtin_amdgcn_mfma_f32_16x16x32_bf16(wqf[mf], xi[nf], aq[mf][nf], 0, 0, 0);
    }

    #pragma unroll
    for (int mf = 0; mf < 2; ++mf) {
        const int cb = cw0 + mf * 16 + 4 * hi4;
        const float4 b4 = *reinterpret_cast<const float4*>(bq + cb);
        const float ba[4] = {b4.x * 0.0625f, b4.y * 0.0625f, b4.z * 0.0625f, b4.w * 0.0625f};
        #pragma unroll
        for (int nf = 0; nf < 4; ++nf) {
            const int tok = t0 + nf * 16 + lo16;
            bf16 tq[4];
            #pragma unroll
            for (int g = 0; g < 4; ++g)
                tq[g] = __float2bfloat16(aq[mf][nf][g] + ba[g]);
            *reinterpret_cast<uint2*>(&qo[((size_t)s * HW + tok) * CDIM + cb]) =
                *reinterpret_cast<uint2*>(tq);
        }
    }
}

// ---------------------------------------------------------------------------
// Kernel 1b: K + V projection (exact round-9 version).
// ---------------------------------------------------------------------------
__global__ __launch_bounds__(256)
void proj_kv_kernel(const float* __restrict__ dep, const bf16* __restrict__ wt,
                    const float* __restrict__ bk, const float* __restrict__ bv,
                    bf16* __restrict__ ko, bf16* __restrict__ vt)
{
    const int bid   = blockIdx.x;
    const int s     = (bid & 7) * 4 + ((bid >> 3) & 3);
    const int tt    = (bid >> 5) & 15;
    const int chalf = bid >> 9;
    const int t0    = tt * 64;

    const int tid  = threadIdx.x;
    const int wave = tid >> 6;
    const int lane = tid & 63;
    const int lo16 = lane & 15;
    const int hi4  = lane >> 4;
    const int cw0  = chalf * 128 + wave * 32;

    __shared__ short Ad[64][40];

    const int so = tid >> 6, st = tid & 63;
    const float* depS = dep + (size_t)s * CDIM * HW + t0;
    const bf16* wtk = wt + (1 << 16);
    const bf16* wtv = wt + (2 << 16);

    f32x4 ak[2][4], av[4][2];
    #pragma unroll
    for (int a = 0; a < 2; ++a)
        #pragma unroll
        for (int b = 0; b < 4; ++b) {
            ak[a][b] = (f32x4){0.f, 0.f, 0.f, 0.f};
            av[b][a] = (f32x4){0.f, 0.f, 0.f, 0.f};
        }

    float rd[8];
    #pragma unroll
    for (int j = 0; j < 8; ++j) rd[j] = depS[(size_t)(so * 8 + j) * HW + st];

    for (int kc = 0; kc < 8; ++kc) {
        __syncthreads();
        {
            short td[8];
            #pragma unroll
            for (int j = 0; j < 8; ++j) {
                bf16 hb = __float2bfloat16(rd[j]);
                td[j] = *reinterpret_cast<short*>(&hb);
            }
            *reinterpret_cast<short8v*>(&Ad[st][so * 8]) = *reinterpret_cast<short8v*>(td);
        }
        __syncthreads();

        if (kc < 7) {
            #pragma unroll
            for (int j = 0; j < 8; ++j)
                rd[j] = depS[(size_t)((kc + 1) * 32 + so * 8 + j) * HW + st];
        }

        short8v xd[4];
        #pragma unroll
        for (int nf = 0; nf < 4; ++nf)
            xd[nf] = *reinterpret_cast<const short8v*>(&Ad[nf * 16 + lo16][hi4 * 8]);

        const int koff = kc * 32 + hi4 * 8;
        short8v wkf[2], wvf[2];
        #pragma unroll
        for (int mf = 0; mf < 2; ++mf) {
            const size_t wrow = (size_t)(cw0 + mf * 16 + lo16) * 256 + koff;
            wkf[mf] = *reinterpret_cast<const short8v*>(wtk + wrow);
            wvf[mf] = *reinterpret_cast<const short8v*>(wtv + wrow);
        }

        #pragma unroll
        for (int mf = 0; mf < 2; ++mf)
            #pragma unroll
            for (int nf = 0; nf < 4; ++nf)
                ak[mf][nf] = __builtin_amdgcn_mfma_f32_16x16x32_bf16(wkf[mf], xd[nf], ak[mf][nf], 0, 0, 0);
        #pragma unroll
        for (int mf = 0; mf < 4; ++mf)
            #pragma unroll
            for (int nf = 0; nf < 2; ++nf)
                av[mf][nf] = __builtin_amdgcn_mfma_f32_16x16x32_bf16(xd[mf], wvf[nf], av[mf][nf], 0, 0, 0);
    }

    #pragma unroll
    for (int mf = 0; mf < 2; ++mf) {
        const int cb = cw0 + mf * 16 + 4 * hi4;
        const float4 b4 = *reinterpret_cast<const float4*>(bk + cb);
        const float ba[4] = {b4.x, b4.y, b4.z, b4.w};
        #pragma unroll
        for (int nf = 0; nf < 4; ++nf) {
            const int tok = t0 + nf * 16 + lo16;
            bf16 tk[4];
            #pragma unroll
            for (int g = 0; g < 4; ++g)
                tk[g] = __float2bfloat16(ak[mf][nf][g] + ba[g]);
            *reinterpret_cast<uint2*>(&ko[((size_t)s * HW + tok) * CDIM + cb]) =
                *reinterpret_cast<uint2*>(tk);
        }
    }
    #pragma unroll
    for (int nf = 0; nf < 2; ++nf) {
        const int c = cw0 + nf * 16 + lo16;
        const float bvv = bv[c];
        #pragma unroll
        for (int mf = 0; mf < 4; ++mf) {
            const int tb = t0 + mf * 16 + 4 * hi4;
            bf16 tv[4];
            #pragma unroll
            for (int g = 0; g < 4; ++g)
                tv[g] = __float2bfloat16(av[mf][nf][g] + bvv);
            *reinterpret_cast<uint2*>(&vt[((size_t)s * CDIM + c) * HW + tb]) =
                *reinterpret_cast<uint2*>(tv);
        }
    }
}

// ---------------------------------------------------------------------------
// Kernel 2: MFMA flash, M=32 rows/wave, KV-SPLIT.
// mode 0: full KV range, direct epilogue (fallback; r13 behavior).
// split : half=(bid>>5)&1 -> KV tokens [half*512, half*512+512).
//   half 0: unnormalized f32 O -> out (scratch reuse) + l0.
//   half 1: bf16 O partial -> part1 + l1. Combiner finalizes.
// No-max softmax partials are additive, so no rescale on combine.
// ---------------------------------------------------------------------------
__global__ __launch_bounds__(256)
void flash_mfma_kernel(const bf16* __restrict__ q, const bf16* __restrict__ k,
                       const bf16* __restrict__ vt, const float* __restrict__ img,
                       float* __restrict__ out, float* __restrict__ l0,
                       float* __restrict__ l1, bf16* __restrict__ part1,
                       int split)
{
    const int bid = blockIdx.x;
    const int s   = (bid & 7) * 4 + ((bid >> 3) & 3);
    int qt, kt0, kt1, mode;
    if (split) {
        const int half = (bid >> 5) & 1;
        qt  = bid >> 6;
        kt0 = half * 16;
        kt1 = kt0 + 16;
        mode = 1 + half;
    } else {
        qt = bid >> 5;
        kt0 = 0; kt1 = 32; mode = 0;
    }
    const int t0 = qt * 128;

    const int tid  = threadIdx.x;
    const int wave = tid >> 6;
    const int lane = tid & 63;
    const int lo16 = lane & 15;
    const int hi4  = lane >> 4;

    __shared__ short KsL[32 * 256];      // 16 KB, chunk ^= (row&7)
    __shared__ short VsL[256 * 32];      // 16 KB, chunk ^= ((row>>1)&3)
    __shared__ short PsL[4 * 2 * 512];   // 8 KB: [wave][mset][16][32] swizzled

    const int rowbase = t0 + wave * 32;

    short8v qf[2][8];
    #pragma unroll
    for (int m = 0; m < 2; ++m) {
        const bf16* qp = q + ((size_t)s * HW + rowbase + m * 16 + lo16) * CDIM + hi4 * 8;
        #pragma unroll
        for (int kf = 0; kf < 8; ++kf)
            qf[m][kf] = *reinterpret_cast<const short8v*>(qp + kf * 32);
    }

    f32x4 Oa[16], Ob[16];
    #pragma unroll
    for (int cf = 0; cf < 16; ++cf) {
        Oa[cf] = (f32x4){0.f, 0.f, 0.f, 0.f};
        Ob[cf] = (f32x4){0.f, 0.f, 0.f, 0.f};
    }
    float lp[2][4] = {{0.f, 0.f, 0.f, 0.f}, {0.f, 0.f, 0.f, 0.f}};

    const bf16* kS  = k  + (size_t)s * HW * CDIM;
    const bf16* vtS = vt + (size_t)s * CDIM * HW;

    const int krow = tid >> 3;
    const int kch  = tid & 7;
    const int kxor = krow & 7;
    const int vxor = (tid >> 1) & 3;

    short8v kreg[4], vreg[4];
    #pragma unroll
    for (int u = 0; u < 4; ++u) {
        kreg[u] = *reinterpret_cast<const short8v*>(
            kS + (size_t)(kt0 * KVT + krow) * CDIM + (kch + 8 * u) * 8);
        vreg[u] = *reinterpret_cast<const short8v*>(
            vtS + (size_t)tid * HW + kt0 * KVT + u * 8);
    }

    const int pvRow = lo16 * 32 + (hi4 ^ ((lo16 >> 1) & 3)) * 8;
    for (int kt = kt0; kt < kt1; ++kt) {
        __syncthreads();
        #pragma unroll
        for (int u = 0; u < 4; ++u)
            *reinterpret_cast<short8v*>(&KsL[krow * 256 + ((kch ^ kxor) + 8 * u) * 8]) = kreg[u];
        #pragma unroll
        for (int u = 0; u < 4; ++u)
            *reinterpret_cast<short8v*>(&VsL[tid * 32 + (u ^ vxor) * 8]) = vreg[u];
        __syncthreads();

        if (kt + 1 < kt1) {
            const bf16* src = kS + (size_t)(kt + 1) * KVT * CDIM;
            #pragma unroll
            for (int u = 0; u < 4; ++u) {
                kreg[u] = *reinterpret_cast<const short8v*>(src + (size_t)krow * CDIM + (kch + 8 * u) * 8);
                vreg[u] = *reinterpret_cast<const short8v*>(vtS + (size_t)tid * HW + (kt + 1) * KVT + u * 8);
            }
        }

        // ---- QK^T: one B-frag read feeds both msets ----
        f32x4 sa[2][2];
        sa[0][0] = (f32x4){0.f, 0.f, 0.f, 0.f};
        sa[0][1] = (f32x4){0.f, 0.f, 0.f, 0.f};
        sa[1][0] = (f32x4){0.f, 0.f, 0.f, 0.f};
        sa[1][1] = (f32x4){0.f, 0.f, 0.f, 0.f};
        __builtin_amdgcn_s_setprio(1);
        #pragma unroll
        for (int ks = 0; ks < 8; ++ks) {
            #pragma unroll
            for (int cf = 0; cf < 2; ++cf) {
                const int row = cf * 16 + lo16;
                const short8v bfr = *reinterpret_cast<const short8v*>(
                    &KsL[row * 256 + ((4 * ks + hi4) ^ (lo16 & 7)) * 8]);
                sa[0][cf] = __builtin_amdgcn_mfma_f32_16x16x32_bf16(qf[0][ks], bfr, sa[0][cf], 0, 0, 0);
                sa[1][cf] = __builtin_amdgcn_mfma_f32_16x16x32_bf16(qf[1][ks], bfr, sa[1][cf], 0, 0, 0);
            }
        }
        __builtin_amdgcn_s_setprio(0);

        // ---- P = exp(S); lane-local l partials; P -> LDS swizzled ----
        #pragma unroll
        for (int m = 0; m < 2; ++m)
            #pragma unroll
            for (int cf = 0; cf < 2; ++cf)
                #pragma unroll
                for (int g = 0; g < 4; ++g) {
                    const float e = __expf(sa[m][cf][g]);
                    lp[m][g] += e;
                    bf16 hb = __float2bfloat16(e);
                    const int r = 4 * hi4 + g;
                    const int ch = (2 * cf + (lo16 >> 3)) ^ ((r >> 1) & 3);
                    PsL[wave * 1024 + m * 512 + r * 32 + ch * 8 + (lo16 & 7)] =
                        *reinterpret_cast<short*>(&hb);
                }

        const short8v pa0 = *reinterpret_cast<const short8v*>(&PsL[wave * 1024 + pvRow]);
        const short8v pa1 = *reinterpret_cast<const short8v*>(&PsL[wave * 1024 + 512 + pvRow]);

        // ---- PV: one V B-frag read feeds both msets ----
        __builtin_amdgcn_s_setprio(1);
        #pragma unroll
        for (int cf = 0; cf < 16; ++cf) {
            const int row = cf * 16 + lo16;
            const short8v vb = *reinterpret_cast<const short8v*>(
                &VsL[row * 32 + (hi4 ^ ((lo16 >> 1) & 3)) * 8]);
            Oa[cf] = __builtin_amdgcn_mfma_f32_16x16x32_bf16(pa0, vb, Oa[cf], 0, 0, 0);
            Ob[cf] = __builtin_amdgcn_mfma_f32_16x16x32_bf16(pa1, vb, Ob[cf], 0, 0, 0);
        }
        __builtin_amdgcn_s_setprio(0);
    }

    // ---- epilogue ----
    const float* imgS = img + (size_t)s * CDIM * HW;
    float*       outS = out + (size_t)s * CDIM * HW;
    #pragma unroll
    for (int m = 0; m < 2; ++m) {
        float lred[4];
        #pragma unroll
        for (int g = 0; g < 4; ++g) {
            float l = lp[m][g];
            #pragma unroll
            for (int off = 1; off < 16; off <<= 1) l += __shfl_xor(l, off);
            lred[g] = l;
        }
        const int tt = rowbase + m * 16 + 4 * hi4;

        if (mode == 0) {
            float inv[4];
            #pragma unroll
            for (int g = 0; g < 4; ++g) inv[g] = 1.0f / lred[g];
            #pragma unroll
            for (int cf = 0; cf < 16; ++cf) {
                const int c = cf * 16 + lo16;
                const f32x4 O = (m == 0) ? Oa[cf] : Ob[cf];
                const float4 r4 = *reinterpret_cast<const float4*>(imgS + (size_t)c * HW + tt);
                float4 o;
                o.x = O[0] * inv[0] + r4.x;
                o.y = O[1] * inv[1] + r4.y;
                o.z = O[2] * inv[2] + r4.z;
                o.w = O[3] * inv[3] + r4.w;
                *reinterpret_cast<float4*>(outS + (size_t)c * HW + tt) = o;
            }
        } else if (mode == 1) {
            if (lo16 == 0) {
                #pragma unroll
                for (int g = 0; g < 4; ++g) l0[s * HW + tt + g] = lred[g];
            }
            #pragma unroll
            for (int cf = 0; cf < 16; ++cf) {
                const int c = cf * 16 + lo16;
                const f32x4 O = (m == 0) ? Oa[cf] : Ob[cf];
                float4 o = {O[0], O[1], O[2], O[3]};
                *reinterpret_cast<float4*>(outS + (size_t)c * HW + tt) = o;
            }
        } else {
            if (lo16 == 0) {
                #pragma unroll
                for (int g = 0; g < 4; ++g) l1[s * HW + tt + g] = lred[g];
            }
            bf16* pS = part1 + (size_t)s * CDIM * HW;
            #pragma unroll
            for (int cf = 0; cf < 16; ++cf) {
                const int c = cf * 16 + lo16;
                const f32x4 O = (m == 0) ? Oa[cf] : Ob[cf];
                bf16 t4[4];
                #pragma unroll
                for (int g = 0; g < 4; ++g) t4[g] = __float2bfloat16(O[g]);
                *reinterpret_cast<uint2*>(pS + (size_t)c * HW + tt) =
                    *reinterpret_cast<uint2*>(t4);
            }
        }
    }
}

// ---------------------------------------------------------------------------
// Kernel 3: combiner (split mode only). out = (out + part1)/(l0+l1) + img.
// Block = (slice, channel); 256 threads x float4 over t. Memory-bound.
// ---------------------------------------------------------------------------
__global__ __launch_bounds__(256)
void combine_kernel(const float* __restrict__ img, const bf16* __restrict__ part1,
                    const float* __restrict__ l0, const float* __restrict__ l1,
                    float* __restrict__ out)
{
    const int bid = blockIdx.x;
    const int s   = (bid & 7) * 4 + ((bid >> 3) & 3);
    const int c   = bid >> 5;
    const int t   = threadIdx.x * 4;

    const size_t base = ((size_t)s * CDIM + c) * HW + t;
    const float4 o0 = *reinterpret_cast<const float4*>(out + base);
    const uint2 p1r = *reinterpret_cast<const uint2*>(part1 + base);
    const unsigned short* pu = (const unsigned short*)&p1r;
    const float4 L0 = *reinterpret_cast<const float4*>(l0 + s * HW + t);
    const float4 L1 = *reinterpret_cast<const float4*>(l1 + s * HW + t);
    const float4 r4 = *reinterpret_cast<const float4*>(img + base);

    float p1f[4];
    #pragma unroll
    for (int j = 0; j < 4; ++j) {
        unsigned int u = ((unsigned int)pu[j]) << 16;
        p1f[j] = *reinterpret_cast<float*>(&u);
    }
    float4 o;
    o.x = (o0.x + p1f[0]) / (L0.x + L1.x) + r4.x;
    o.y = (o0.y + p1f[1]) / (L0.y + L1.y) + r4.y;
    o.z = (o0.z + p1f[2]) / (L0.z + L1.z) + r4.z;
    o.w = (o0.w + p1f[3]) / (L0.w + L1.w) + r4.w;
    *reinterpret_cast<float4*>(out + base) = o;
}

// ---------------------------------------------------------------------------
extern "C" void kernel_launch(void* const* d_in, const int* in_sizes, int n_in,
                              void* d_out, int out_size, void* d_ws, size_t ws_size,
                              hipStream_t stream)
{
    const float* img = (const float*)d_in[0];
    const float* dep = (const float*)d_in[1];
    const float* Wq  = (const float*)d_in[2];
    const float* bq  = (const float*)d_in[3];
    const float* Wk  = (const float*)d_in[4];
    const float* bk  = (const float*)d_in[5];
    const float* Wv  = (const float*)d_in[6];
    const float* bv  = (const float*)d_in[7];
    float* out = (float*)d_out;

    const size_t npt = (size_t)NSLICE * HW * CDIM;
    const size_t base_need  = 3 * npt * sizeof(bf16) + 3 * 65536 * sizeof(bf16);
    const size_t split_need = base_need + 2 * (size_t)NSLICE * HW * sizeof(float)
                            + npt * sizeof(bf16);
    if (ws_size < base_need) {
        hipMemsetAsync(d_out, 0, (size_t)out_size * sizeof(float), stream);
        return;
    }
    const int split = (ws_size >= split_need) ? 1 : 0;

    bf16* q  = (bf16*)d_ws;        // token-major, prescaled
    bf16* k  = q + npt;            // token-major
    bf16* vt = k + npt;            // channel-major
    bf16* wt = vt + npt;           // [3][256][256] W^T
    float* l0 = (float*)(wt + 3 * 65536);
    float* l1 = l0 + (size_t)NSLICE * HW;
    bf16* part1 = (bf16*)(l1 + (size_t)NSLICE * HW);

    wt_prep_kernel<<<dim3(3 * 256), 256, 0, stream>>>(Wq, Wk, Wv, wt);

    proj_q_kernel<<<dim3(NSLICE * 32), 256, 0, stream>>>(img, wt, bq, q);
    proj_kv_kernel<<<dim3(NSLICE * 32), 256, 0, stream>>>(dep, wt, bk, bv, k, vt);

    if (split) {
        flash_mfma_kernel<<<dim3(NSLICE * 16), 256, 0, stream>>>(
            q, k, vt, img, out, l0, l1, part1, 1);
        combine_kernel<<<dim3(NSLICE * CDIM), 256, 0, stream>>>(img, part1, l0, l1, out);
    } else {
        flash_mfma_kernel<<<dim3(NSLICE * 8), 256, 0, stream>>>(
            q, k, vt, img, out, l0, l1, part1, 0);
    }
}

// Round 15
// 132.121 us; speedup vs baseline: 1.1562x; 1.1562x over previous
//
#include <hip/hip_runtime.h>
#include <hip/hip_bf16.h>

typedef __hip_bfloat16 bf16;
typedef __attribute__((ext_vector_type(8))) short short8v;
typedef __attribute__((ext_vector_type(4))) float f32x4;

#define NSLICE 32   // B*S
#define HW     1024 // H*W
#define CDIM   256  // C1 == C2 == C
#define KVT    32   // kv tokens per flash inner tile

// ---------------------------------------------------------------------------
// Kernel 0: W^T prep. W f32 [cin][cout] -> wt bf16 [mat][cout][cin].
// Wq (mat 0) prescaled by 1/16.
// ---------------------------------------------------------------------------
__global__ __launch_bounds__(256)
void wt_prep_kernel(const float* __restrict__ Wq, const float* __restrict__ Wk,
                    const float* __restrict__ Wv, bf16* __restrict__ wt)
{
    const int m = blockIdx.x >> 8;
    const int r = blockIdx.x & 255;
    const int tid = threadIdx.x;
    const float* W = (m == 0) ? Wq : (m == 1) ? Wk : Wv;
    const float sc = (m == 0) ? 0.0625f : 1.0f;
    wt[((size_t)m << 16) + (size_t)tid * 256 + r] = __float2bfloat16(W[r * 256 + tid] * sc);
}

// ---------------------------------------------------------------------------
// Kernel 1a: Q projection (exact round-9 version).
// ---------------------------------------------------------------------------
__global__ __launch_bounds__(256)
void proj_q_kernel(const float* __restrict__ img, const bf16* __restrict__ wt,
                   const float* __restrict__ bq, bf16* __restrict__ qo)
{
    const int bid   = blockIdx.x;
    const int s     = (bid & 7) * 4 + ((bid >> 3) & 3);
    const int tt    = (bid >> 5) & 15;
    const int chalf = bid >> 9;
    const int t0    = tt * 64;

    const int tid  = threadIdx.x;
    const int wave = tid >> 6;
    const int lane = tid & 63;
    const int lo16 = lane & 15;
    const int hi4  = lane >> 4;
    const int cw0  = chalf * 128 + wave * 32;

    __shared__ short Ai[64][40];

    const int so = tid >> 6, st = tid & 63;
    const float* imgS = img + (size_t)s * CDIM * HW + t0;

    f32x4 aq[2][4];
    #pragma unroll
    for (int a = 0; a < 2; ++a)
        #pragma unroll
        for (int b = 0; b < 4; ++b) aq[a][b] = (f32x4){0.f, 0.f, 0.f, 0.f};

    float ri[8];
    #pragma unroll
    for (int j = 0; j < 8; ++j) ri[j] = imgS[(size_t)(so * 8 + j) * HW + st];

    for (int kc = 0; kc < 8; ++kc) {
        __syncthreads();
        {
            short ti[8];
            #pragma unroll
            for (int j = 0; j < 8; ++j) {
                bf16 hb = __float2bfloat16(ri[j]);
                ti[j] = *reinterpret_cast<short*>(&hb);
            }
            *reinterpret_cast<short8v*>(&Ai[st][so * 8]) = *reinterpret_cast<short8v*>(ti);
        }
        __syncthreads();

        if (kc < 7) {
            #pragma unroll
            for (int j = 0; j < 8; ++j)
                ri[j] = imgS[(size_t)((kc + 1) * 32 + so * 8 + j) * HW + st];
        }

        short8v xi[4];
        #pragma unroll
        for (int nf = 0; nf < 4; ++nf)
            xi[nf] = *reinterpret_cast<const short8v*>(&Ai[nf * 16 + lo16][hi4 * 8]);

        const int koff = kc * 32 + hi4 * 8;
        short8v wqf[2];
        #pragma unroll
        for (int mf = 0; mf < 2; ++mf)
            wqf[mf] = *reinterpret_cast<const short8v*>(
                wt + (size_t)(cw0 + mf * 16 + lo16) * 256 + koff);

        #pragma unroll
        for (int mf = 0; mf < 2; ++mf)
            #pragma unroll
            for (int nf = 0; nf < 4; ++nf)
                aq[mf][nf] = __builtin_amdgcn_mfma_f32_16x16x32_bf16(wqf[mf], xi[nf], aq[mf][nf], 0, 0, 0);
    }

    #pragma unroll
    for (int mf = 0; mf < 2; ++mf) {
        const int cb = cw0 + mf * 16 + 4 * hi4;
        const float4 b4 = *reinterpret_cast<const float4*>(bq + cb);
        const float ba[4] = {b4.x * 0.0625f, b4.y * 0.0625f, b4.z * 0.0625f, b4.w * 0.0625f};
        #pragma unroll
        for (int nf = 0; nf < 4; ++nf) {
            const int tok = t0 + nf * 16 + lo16;
            bf16 tq[4];
            #pragma unroll
            for (int g = 0; g < 4; ++g)
                tq[g] = __float2bfloat16(aq[mf][nf][g] + ba[g]);
            *reinterpret_cast<uint2*>(&qo[((size_t)s * HW + tok) * CDIM + cb]) =
                *reinterpret_cast<uint2*>(tq);
        }
    }
}

// ---------------------------------------------------------------------------
// Kernel 1b: K + V projection (exact round-9 version).
// ---------------------------------------------------------------------------
__global__ __launch_bounds__(256)
void proj_kv_kernel(const float* __restrict__ dep, const bf16* __restrict__ wt,
                    const float* __restrict__ bk, const float* __restrict__ bv,
                    bf16* __restrict__ ko, bf16* __restrict__ vt)
{
    const int bid   = blockIdx.x;
    const int s     = (bid & 7) * 4 + ((bid >> 3) & 3);
    const int tt    = (bid >> 5) & 15;
    const int chalf = bid >> 9;
    const int t0    = tt * 64;

    const int tid  = threadIdx.x;
    const int wave = tid >> 6;
    const int lane = tid & 63;
    const int lo16 = lane & 15;
    const int hi4  = lane >> 4;
    const int cw0  = chalf * 128 + wave * 32;

    __shared__ short Ad[64][40];

    const int so = tid >> 6, st = tid & 63;
    const float* depS = dep + (size_t)s * CDIM * HW + t0;
    const bf16* wtk = wt + (1 << 16);
    const bf16* wtv = wt + (2 << 16);

    f32x4 ak[2][4], av[4][2];
    #pragma unroll
    for (int a = 0; a < 2; ++a)
        #pragma unroll
        for (int b = 0; b < 4; ++b) {
            ak[a][b] = (f32x4){0.f, 0.f, 0.f, 0.f};
            av[b][a] = (f32x4){0.f, 0.f, 0.f, 0.f};
        }

    float rd[8];
    #pragma unroll
    for (int j = 0; j < 8; ++j) rd[j] = depS[(size_t)(so * 8 + j) * HW + st];

    for (int kc = 0; kc < 8; ++kc) {
        __syncthreads();
        {
            short td[8];
            #pragma unroll
            for (int j = 0; j < 8; ++j) {
                bf16 hb = __float2bfloat16(rd[j]);
                td[j] = *reinterpret_cast<short*>(&hb);
            }
            *reinterpret_cast<short8v*>(&Ad[st][so * 8]) = *reinterpret_cast<short8v*>(td);
        }
        __syncthreads();

        if (kc < 7) {
            #pragma unroll
            for (int j = 0; j < 8; ++j)
                rd[j] = depS[(size_t)((kc + 1) * 32 + so * 8 + j) * HW + st];
        }

        short8v xd[4];
        #pragma unroll
        for (int nf = 0; nf < 4; ++nf)
            xd[nf] = *reinterpret_cast<const short8v*>(&Ad[nf * 16 + lo16][hi4 * 8]);

        const int koff = kc * 32 + hi4 * 8;
        short8v wkf[2], wvf[2];
        #pragma unroll
        for (int mf = 0; mf < 2; ++mf) {
            const size_t wrow = (size_t)(cw0 + mf * 16 + lo16) * 256 + koff;
            wkf[mf] = *reinterpret_cast<const short8v*>(wtk + wrow);
            wvf[mf] = *reinterpret_cast<const short8v*>(wtv + wrow);
        }

        #pragma unroll
        for (int mf = 0; mf < 2; ++mf)
            #pragma unroll
            for (int nf = 0; nf < 4; ++nf)
                ak[mf][nf] = __builtin_amdgcn_mfma_f32_16x16x32_bf16(wkf[mf], xd[nf], ak[mf][nf], 0, 0, 0);
        #pragma unroll
        for (int mf = 0; mf < 4; ++mf)
            #pragma unroll
            for (int nf = 0; nf < 2; ++nf)
                av[mf][nf] = __builtin_amdgcn_mfma_f32_16x16x32_bf16(xd[mf], wvf[nf], av[mf][nf], 0, 0, 0);
    }

    #pragma unroll
    for (int mf = 0; mf < 2; ++mf) {
        const int cb = cw0 + mf * 16 + 4 * hi4;
        const float4 b4 = *reinterpret_cast<const float4*>(bk + cb);
        const float ba[4] = {b4.x, b4.y, b4.z, b4.w};
        #pragma unroll
        for (int nf = 0; nf < 4; ++nf) {
            const int tok = t0 + nf * 16 + lo16;
            bf16 tk[4];
            #pragma unroll
            for (int g = 0; g < 4; ++g)
                tk[g] = __float2bfloat16(ak[mf][nf][g] + ba[g]);
            *reinterpret_cast<uint2*>(&ko[((size_t)s * HW + tok) * CDIM + cb]) =
                *reinterpret_cast<uint2*>(tk);
        }
    }
    #pragma unroll
    for (int nf = 0; nf < 2; ++nf) {
        const int c = cw0 + nf * 16 + lo16;
        const float bvv = bv[c];
        #pragma unroll
        for (int mf = 0; mf < 4; ++mf) {
            const int tb = t0 + mf * 16 + 4 * hi4;
            bf16 tv[4];
            #pragma unroll
            for (int g = 0; g < 4; ++g)
                tv[g] = __float2bfloat16(av[mf][nf][g] + bvv);
            *reinterpret_cast<uint2*>(&vt[((size_t)s * CDIM + c) * HW + tb]) =
                *reinterpret_cast<uint2*>(tv);
        }
    }
}

// ---------------------------------------------------------------------------
// Kernel 2: MFMA flash, 2M x 2N wave split. Block = 64 q-rows; wave =
// 32 rows x 128 cols (wave_m row group, wave_n col half). K reads unchanged,
// V reads halved per wave; acc = 64 VGPR (fits 2 waves/SIMD at grid 512).
// KVT=32, no-max softmax, XOR-swizzled LDS, register prefetch, setprio —
// all exactly as round 9.
// ---------------------------------------------------------------------------
__global__ __launch_bounds__(256)
void flash_mfma_kernel(const bf16* __restrict__ q, const bf16* __restrict__ k,
                       const bf16* __restrict__ vt, const float* __restrict__ img,
                       float* __restrict__ out)
{
    const int bid = blockIdx.x;
    const int s   = (bid & 7) * 4 + ((bid >> 3) & 3);
    const int t0  = (bid >> 5) * 64;

    const int tid  = threadIdx.x;
    const int wave = tid >> 6;
    const int wm   = wave >> 1;       // row group (0..1)
    const int wn   = wave & 1;        // col half (0..1)
    const int lane = tid & 63;
    const int lo16 = lane & 15;
    const int hi4  = lane >> 4;

    __shared__ short KsL[32 * 256];      // 16 KB, chunk ^= (row&7)
    __shared__ short VsL[256 * 32];      // 16 KB, chunk ^= ((row>>1)&3)
    __shared__ short PsL[4 * 2 * 512];   // 8 KB: [wave][mset][16][32] swizzled

    const int rowbase = t0 + wm * 32;

    short8v qf[2][8];
    #pragma unroll
    for (int m = 0; m < 2; ++m) {
        const bf16* qp = q + ((size_t)s * HW + rowbase + m * 16 + lo16) * CDIM + hi4 * 8;
        #pragma unroll
        for (int kf = 0; kf < 8; ++kf)
            qf[m][kf] = *reinterpret_cast<const short8v*>(qp + kf * 32);
    }

    f32x4 Oa[8], Ob[8];
    #pragma unroll
    for (int cf = 0; cf < 8; ++cf) {
        Oa[cf] = (f32x4){0.f, 0.f, 0.f, 0.f};
        Ob[cf] = (f32x4){0.f, 0.f, 0.f, 0.f};
    }
    float lp[2][4] = {{0.f, 0.f, 0.f, 0.f}, {0.f, 0.f, 0.f, 0.f}};

    const bf16* kS  = k  + (size_t)s * HW * CDIM;
    const bf16* vtS = vt + (size_t)s * CDIM * HW;

    const int krow = tid >> 3;
    const int kch  = tid & 7;
    const int kxor = krow & 7;
    const int vxor = (tid >> 1) & 3;

    short8v kreg[4], vreg[4];
    #pragma unroll
    for (int u = 0; u < 4; ++u) {
        kreg[u] = *reinterpret_cast<const short8v*>(kS + (size_t)krow * CDIM + (kch + 8 * u) * 8);
        vreg[u] = *reinterpret_cast<const short8v*>(vtS + (size_t)tid * HW + u * 8);
    }

    const int pvRow = lo16 * 32 + (hi4 ^ ((lo16 >> 1) & 3)) * 8;
    for (int kt = 0; kt < HW / KVT; ++kt) {
        __syncthreads();
        #pragma unroll
        for (int u = 0; u < 4; ++u)
            *reinterpret_cast<short8v*>(&KsL[krow * 256 + ((kch ^ kxor) + 8 * u) * 8]) = kreg[u];
        #pragma unroll
        for (int u = 0; u < 4; ++u)
            *reinterpret_cast<short8v*>(&VsL[tid * 32 + (u ^ vxor) * 8]) = vreg[u];
        __syncthreads();

        if (kt + 1 < HW / KVT) {
            const bf16* src = kS + (size_t)(kt + 1) * KVT * CDIM;
            #pragma unroll
            for (int u = 0; u < 4; ++u) {
                kreg[u] = *reinterpret_cast<const short8v*>(src + (size_t)krow * CDIM + (kch + 8 * u) * 8);
                vreg[u] = *reinterpret_cast<const short8v*>(vtS + (size_t)tid * HW + (kt + 1) * KVT + u * 8);
            }
        }

        // ---- QK^T: S[32 x 32] per wave; one B-frag read feeds both msets ----
        f32x4 sa[2][2];
        sa[0][0] = (f32x4){0.f, 0.f, 0.f, 0.f};
        sa[0][1] = (f32x4){0.f, 0.f, 0.f, 0.f};
        sa[1][0] = (f32x4){0.f, 0.f, 0.f, 0.f};
        sa[1][1] = (f32x4){0.f, 0.f, 0.f, 0.f};
        __builtin_amdgcn_s_setprio(1);
        #pragma unroll
        for (int ks = 0; ks < 8; ++ks) {
            #pragma unroll
            for (int cf = 0; cf < 2; ++cf) {
                const int row = cf * 16 + lo16;
                const short8v bfr = *reinterpret_cast<const short8v*>(
                    &KsL[row * 256 + ((4 * ks + hi4) ^ (lo16 & 7)) * 8]);
                sa[0][cf] = __builtin_amdgcn_mfma_f32_16x16x32_bf16(qf[0][ks], bfr, sa[0][cf], 0, 0, 0);
                sa[1][cf] = __builtin_amdgcn_mfma_f32_16x16x32_bf16(qf[1][ks], bfr, sa[1][cf], 0, 0, 0);
            }
        }
        __builtin_amdgcn_s_setprio(0);

        // ---- P = exp(S); lane-local l partials; P -> LDS swizzled ----
        #pragma unroll
        for (int m = 0; m < 2; ++m)
            #pragma unroll
            for (int cf = 0; cf < 2; ++cf)
                #pragma unroll
                for (int g = 0; g < 4; ++g) {
                    const float e = __expf(sa[m][cf][g]);
                    lp[m][g] += e;
                    bf16 hb = __float2bfloat16(e);
                    const int r = 4 * hi4 + g;
                    const int ch = (2 * cf + (lo16 >> 3)) ^ ((r >> 1) & 3);
                    PsL[wave * 1024 + m * 512 + r * 32 + ch * 8 + (lo16 & 7)] =
                        *reinterpret_cast<short*>(&hb);
                }

        const short8v pa0 = *reinterpret_cast<const short8v*>(&PsL[wave * 1024 + pvRow]);
        const short8v pa1 = *reinterpret_cast<const short8v*>(&PsL[wave * 1024 + 512 + pvRow]);

        // ---- PV: O[32 x 128] += P[32 x 32] @ V[32 x 128] (wave's col half) ----
        __builtin_amdgcn_s_setprio(1);
        #pragma unroll
        for (int cf = 0; cf < 8; ++cf) {
            const int row = (wn * 8 + cf) * 16 + lo16;
            const short8v vb = *reinterpret_cast<const short8v*>(
                &VsL[row * 32 + (hi4 ^ ((lo16 >> 1) & 3)) * 8]);
            Oa[cf] = __builtin_amdgcn_mfma_f32_16x16x32_bf16(pa0, vb, Oa[cf], 0, 0, 0);
            Ob[cf] = __builtin_amdgcn_mfma_f32_16x16x32_bf16(pa1, vb, Ob[cf], 0, 0, 0);
        }
        __builtin_amdgcn_s_setprio(0);
    }

    // ---- epilogue: each wave owns 32 rows x 128 cols ----
    const float* imgS = img + (size_t)s * CDIM * HW;
    float*       outS = out + (size_t)s * CDIM * HW;
    #pragma unroll
    for (int m = 0; m < 2; ++m) {
        float inv[4];
        #pragma unroll
        for (int g = 0; g < 4; ++g) {
            float l = lp[m][g];
            #pragma unroll
            for (int off = 1; off < 16; off <<= 1) l += __shfl_xor(l, off);
            inv[g] = 1.0f / l;
        }
        const int tt = rowbase + m * 16 + 4 * hi4;
        #pragma unroll
        for (int cf = 0; cf < 8; ++cf) {
            const int c = (wn * 8 + cf) * 16 + lo16;
            const f32x4 O = (m == 0) ? Oa[cf] : Ob[cf];
            const float4 r4 = *reinterpret_cast<const float4*>(imgS + (size_t)c * HW + tt);
            float4 o;
            o.x = O[0] * inv[0] + r4.x;
            o.y = O[1] * inv[1] + r4.y;
            o.z = O[2] * inv[2] + r4.z;
            o.w = O[3] * inv[3] + r4.w;
            *reinterpret_cast<float4*>(outS + (size_t)c * HW + tt) = o;
        }
    }
}

// ---------------------------------------------------------------------------
extern "C" void kernel_launch(void* const* d_in, const int* in_sizes, int n_in,
                              void* d_out, int out_size, void* d_ws, size_t ws_size,
                              hipStream_t stream)
{
    const float* img = (const float*)d_in[0];
    const float* dep = (const float*)d_in[1];
    const float* Wq  = (const float*)d_in[2];
    const float* bq  = (const float*)d_in[3];
    const float* Wk  = (const float*)d_in[4];
    const float* bk  = (const float*)d_in[5];
    const float* Wv  = (const float*)d_in[6];
    const float* bv  = (const float*)d_in[7];
    float* out = (float*)d_out;

    const size_t npt  = (size_t)NSLICE * HW * CDIM;
    const size_t need = 3 * npt * sizeof(bf16) + 3 * 65536 * sizeof(bf16);
    if (ws_size < need) {
        hipMemsetAsync(d_out, 0, (size_t)out_size * sizeof(float), stream);
        return;
    }

    bf16* q  = (bf16*)d_ws;        // token-major, prescaled
    bf16* k  = q + npt;            // token-major
    bf16* vt = k + npt;            // channel-major
    bf16* wt = vt + npt;           // [3][256][256] W^T

    wt_prep_kernel<<<dim3(3 * 256), 256, 0, stream>>>(Wq, Wk, Wv, wt);

    proj_q_kernel<<<dim3(NSLICE * 32), 256, 0, stream>>>(img, wt, bq, q);
    proj_kv_kernel<<<dim3(NSLICE * 32), 256, 0, stream>>>(dep, wt, bk, bv, k, vt);

    flash_mfma_kernel<<<dim3(NSLICE * 16), 256, 0, stream>>>(q, k, vt, img, out);
}

// Round 16
// 122.716 us; speedup vs baseline: 1.2449x; 1.0766x over previous
//
#include <hip/hip_runtime.h>
#include <hip/hip_bf16.h>

typedef __hip_bfloat16 bf16;
typedef __attribute__((ext_vector_type(8))) short short8v;
typedef __attribute__((ext_vector_type(4))) float f32x4;

#define NSLICE 32   // B*S
#define HW     1024 // H*W
#define CDIM   256  // C1 == C2 == C
#define KVT    32   // kv tokens per flash inner tile
#define NKT    (HW / KVT)

// dynamic LDS layout (shorts): K0=0, K1=8192, V0=16384, V1=24576, Ps=32768
#define FLASH_LDS_BYTES ((32768 + 2048) * 2)

// ---------------------------------------------------------------------------
// Kernel 0: W^T prep. W f32 [cin][cout] -> wt bf16 [mat][cout][cin].
// Wq (mat 0) prescaled by 1/16.
// ---------------------------------------------------------------------------
__global__ __launch_bounds__(256)
void wt_prep_kernel(const float* __restrict__ Wq, const float* __restrict__ Wk,
                    const float* __restrict__ Wv, bf16* __restrict__ wt)
{
    const int m = blockIdx.x >> 8;
    const int r = blockIdx.x & 255;
    const int tid = threadIdx.x;
    const float* W = (m == 0) ? Wq : (m == 1) ? Wk : Wv;
    const float sc = (m == 0) ? 0.0625f : 1.0f;
    wt[((size_t)m << 16) + (size_t)tid * 256 + r] = __float2bfloat16(W[r * 256 + tid] * sc);
}

// ---------------------------------------------------------------------------
// Kernel 1a: Q projection (exact round-9 version).
// ---------------------------------------------------------------------------
__global__ __launch_bounds__(256)
void proj_q_kernel(const float* __restrict__ img, const bf16* __restrict__ wt,
                   const float* __restrict__ bq, bf16* __restrict__ qo)
{
    const int bid   = blockIdx.x;
    const int s     = (bid & 7) * 4 + ((bid >> 3) & 3);
    const int tt    = (bid >> 5) & 15;
    const int chalf = bid >> 9;
    const int t0    = tt * 64;

    const int tid  = threadIdx.x;
    const int wave = tid >> 6;
    const int lane = tid & 63;
    const int lo16 = lane & 15;
    const int hi4  = lane >> 4;
    const int cw0  = chalf * 128 + wave * 32;

    __shared__ short Ai[64][40];

    const int so = tid >> 6, st = tid & 63;
    const float* imgS = img + (size_t)s * CDIM * HW + t0;

    f32x4 aq[2][4];
    #pragma unroll
    for (int a = 0; a < 2; ++a)
        #pragma unroll
        for (int b = 0; b < 4; ++b) aq[a][b] = (f32x4){0.f, 0.f, 0.f, 0.f};

    float ri[8];
    #pragma unroll
    for (int j = 0; j < 8; ++j) ri[j] = imgS[(size_t)(so * 8 + j) * HW + st];

    for (int kc = 0; kc < 8; ++kc) {
        __syncthreads();
        {
            short ti[8];
            #pragma unroll
            for (int j = 0; j < 8; ++j) {
                bf16 hb = __float2bfloat16(ri[j]);
                ti[j] = *reinterpret_cast<short*>(&hb);
            }
            *reinterpret_cast<short8v*>(&Ai[st][so * 8]) = *reinterpret_cast<short8v*>(ti);
        }
        __syncthreads();

        if (kc < 7) {
            #pragma unroll
            for (int j = 0; j < 8; ++j)
                ri[j] = imgS[(size_t)((kc + 1) * 32 + so * 8 + j) * HW + st];
        }

        short8v xi[4];
        #pragma unroll
        for (int nf = 0; nf < 4; ++nf)
            xi[nf] = *reinterpret_cast<const short8v*>(&Ai[nf * 16 + lo16][hi4 * 8]);

        const int koff = kc * 32 + hi4 * 8;
        short8v wqf[2];
        #pragma unroll
        for (int mf = 0; mf < 2; ++mf)
            wqf[mf] = *reinterpret_cast<const short8v*>(
                wt + (size_t)(cw0 + mf * 16 + lo16) * 256 + koff);

        #pragma unroll
        for (int mf = 0; mf < 2; ++mf)
            #pragma unroll
            for (int nf = 0; nf < 4; ++nf)
                aq[mf][nf] = __builtin_amdgcn_mfma_f32_16x16x32_bf16(wqf[mf], xi[nf], aq[mf][nf], 0, 0, 0);
    }

    #pragma unroll
    for (int mf = 0; mf < 2; ++mf) {
        const int cb = cw0 + mf * 16 + 4 * hi4;
        const float4 b4 = *reinterpret_cast<const float4*>(bq + cb);
        const float ba[4] = {b4.x * 0.0625f, b4.y * 0.0625f, b4.z * 0.0625f, b4.w * 0.0625f};
        #pragma unroll
        for (int nf = 0; nf < 4; ++nf) {
            const int tok = t0 + nf * 16 + lo16;
            bf16 tq[4];
            #pragma unroll
            for (int g = 0; g < 4; ++g)
                tq[g] = __float2bfloat16(aq[mf][nf][g] + ba[g]);
            *reinterpret_cast<uint2*>(&qo[((size_t)s * HW + tok) * CDIM + cb]) =
                *reinterpret_cast<uint2*>(tq);
        }
    }
}

// ---------------------------------------------------------------------------
// Kernel 1b: K + V projection (exact round-9 version).
// ---------------------------------------------------------------------------
__global__ __launch_bounds__(256)
void proj_kv_kernel(const float* __restrict__ dep, const bf16* __restrict__ wt,
                    const float* __restrict__ bk, const float* __restrict__ bv,
                    bf16* __restrict__ ko, bf16* __restrict__ vt)
{
    const int bid   = blockIdx.x;
    const int s     = (bid & 7) * 4 + ((bid >> 3) & 3);
    const int tt    = (bid >> 5) & 15;
    const int chalf = bid >> 9;
    const int t0    = tt * 64;

    const int tid  = threadIdx.x;
    const int wave = tid >> 6;
    const int lane = tid & 63;
    const int lo16 = lane & 15;
    const int hi4  = lane >> 4;
    const int cw0  = chalf * 128 + wave * 32;

    __shared__ short Ad[64][40];

    const int so = tid >> 6, st = tid & 63;
    const float* depS = dep + (size_t)s * CDIM * HW + t0;
    const bf16* wtk = wt + (1 << 16);
    const bf16* wtv = wt + (2 << 16);

    f32x4 ak[2][4], av[4][2];
    #pragma unroll
    for (int a = 0; a < 2; ++a)
        #pragma unroll
        for (int b = 0; b < 4; ++b) {
            ak[a][b] = (f32x4){0.f, 0.f, 0.f, 0.f};
            av[b][a] = (f32x4){0.f, 0.f, 0.f, 0.f};
        }

    float rd[8];
    #pragma unroll
    for (int j = 0; j < 8; ++j) rd[j] = depS[(size_t)(so * 8 + j) * HW + st];

    for (int kc = 0; kc < 8; ++kc) {
        __syncthreads();
        {
            short td[8];
            #pragma unroll
            for (int j = 0; j < 8; ++j) {
                bf16 hb = __float2bfloat16(rd[j]);
                td[j] = *reinterpret_cast<short*>(&hb);
            }
            *reinterpret_cast<short8v*>(&Ad[st][so * 8]) = *reinterpret_cast<short8v*>(td);
        }
        __syncthreads();

        if (kc < 7) {
            #pragma unroll
            for (int j = 0; j < 8; ++j)
                rd[j] = depS[(size_t)((kc + 1) * 32 + so * 8 + j) * HW + st];
        }

        short8v xd[4];
        #pragma unroll
        for (int nf = 0; nf < 4; ++nf)
            xd[nf] = *reinterpret_cast<const short8v*>(&Ad[nf * 16 + lo16][hi4 * 8]);

        const int koff = kc * 32 + hi4 * 8;
        short8v wkf[2], wvf[2];
        #pragma unroll
        for (int mf = 0; mf < 2; ++mf) {
            const size_t wrow = (size_t)(cw0 + mf * 16 + lo16) * 256 + koff;
            wkf[mf] = *reinterpret_cast<const short8v*>(wtk + wrow);
            wvf[mf] = *reinterpret_cast<const short8v*>(wtv + wrow);
        }

        #pragma unroll
        for (int mf = 0; mf < 2; ++mf)
            #pragma unroll
            for (int nf = 0; nf < 4; ++nf)
                ak[mf][nf] = __builtin_amdgcn_mfma_f32_16x16x32_bf16(wkf[mf], xd[nf], ak[mf][nf], 0, 0, 0);
        #pragma unroll
        for (int mf = 0; mf < 4; ++mf)
            #pragma unroll
            for (int nf = 0; nf < 2; ++nf)
                av[mf][nf] = __builtin_amdgcn_mfma_f32_16x16x32_bf16(xd[mf], wvf[nf], av[mf][nf], 0, 0, 0);
    }

    #pragma unroll
    for (int mf = 0; mf < 2; ++mf) {
        const int cb = cw0 + mf * 16 + 4 * hi4;
        const float4 b4 = *reinterpret_cast<const float4*>(bk + cb);
        const float ba[4] = {b4.x, b4.y, b4.z, b4.w};
        #pragma unroll
        for (int nf = 0; nf < 4; ++nf) {
            const int tok = t0 + nf * 16 + lo16;
            bf16 tk[4];
            #pragma unroll
            for (int g = 0; g < 4; ++g)
                tk[g] = __float2bfloat16(ak[mf][nf][g] + ba[g]);
            *reinterpret_cast<uint2*>(&ko[((size_t)s * HW + tok) * CDIM + cb]) =
                *reinterpret_cast<uint2*>(tk);
        }
    }
    #pragma unroll
    for (int nf = 0; nf < 2; ++nf) {
        const int c = cw0 + nf * 16 + lo16;
        const float bvv = bv[c];
        #pragma unroll
        for (int mf = 0; mf < 4; ++mf) {
            const int tb = t0 + mf * 16 + 4 * hi4;
            bf16 tv[4];
            #pragma unroll
            for (int g = 0; g < 4; ++g)
                tv[g] = __float2bfloat16(av[mf][nf][g] + bvv);
            *reinterpret_cast<uint2*>(&vt[((size_t)s * CDIM + c) * HW + tb]) =
                *reinterpret_cast<uint2*>(tv);
        }
    }
}

// ---------------------------------------------------------------------------
// Kernel 2: MFMA flash attention — round-9 structure with DOUBLE-BUFFERED
// K/V LDS (dynamic 68 KB). One barrier per KV tile instead of two: the
// ds_writes of tile kt+1 go to the idle buffer and overlap with QK/softmax/
// PV on the current buffer. Wave = 16 rows x 256 cols, no-max softmax,
// XOR-swizzled LDS, register prefetch, setprio — all exactly round 9.
// ---------------------------------------------------------------------------
__global__ __launch_bounds__(256)
void flash_mfma_kernel(const bf16* __restrict__ q, const bf16* __restrict__ k,
                       const bf16* __restrict__ vt, const float* __restrict__ img,
                       float* __restrict__ out)
{
    const int bid = blockIdx.x;
    const int s   = (bid & 7) * 4 + ((bid >> 3) & 3);
    const int t0  = (bid >> 5) * 64;

    const int tid  = threadIdx.x;
    const int wave = tid >> 6;
    const int lane = tid & 63;
    const int lo16 = lane & 15;
    const int hi4  = lane >> 4;

    extern __shared__ short SM[];
    // K buffers at 0 / 8192, V buffers at 16384 / 24576, Ps at 32768

    short8v qf[8];
    {
        const bf16* qp = q + ((size_t)s * HW + t0 + wave * 16 + lo16) * CDIM + hi4 * 8;
        #pragma unroll
        for (int kf = 0; kf < 8; ++kf)
            qf[kf] = *reinterpret_cast<const short8v*>(qp + kf * 32);
    }

    f32x4 Oacc[16];
    #pragma unroll
    for (int cf = 0; cf < 16; ++cf) Oacc[cf] = (f32x4){0.f, 0.f, 0.f, 0.f};
    float lp[4] = {0.f, 0.f, 0.f, 0.f};

    const bf16* kS  = k  + (size_t)s * HW * CDIM;
    const bf16* vtS = vt + (size_t)s * CDIM * HW;

    const int krow = tid >> 3;
    const int kch  = tid & 7;
    const int kxor = krow & 7;
    const int vxor = (tid >> 1) & 3;

    short8v kreg[4], vreg[4];
    #pragma unroll
    for (int u = 0; u < 4; ++u) {
        kreg[u] = *reinterpret_cast<const short8v*>(kS + (size_t)krow * CDIM + (kch + 8 * u) * 8);
        vreg[u] = *reinterpret_cast<const short8v*>(vtS + (size_t)tid * HW + u * 8);
    }

    // prologue: publish tile 0 into buffer 0
    #pragma unroll
    for (int u = 0; u < 4; ++u)
        *reinterpret_cast<short8v*>(&SM[krow * 256 + ((kch ^ kxor) + 8 * u) * 8]) = kreg[u];
    #pragma unroll
    for (int u = 0; u < 4; ++u)
        *reinterpret_cast<short8v*>(&SM[16384 + tid * 32 + (u ^ vxor) * 8]) = vreg[u];
    __syncthreads();

    const int pvRow = lo16 * 32 + (hi4 ^ ((lo16 >> 1) & 3)) * 8;
    for (int kt = 0; kt < NKT; ++kt) {
        const int cur = kt & 1;
        const int nxt = cur ^ 1;
        short* Kc = SM + cur * 8192;
        short* Vc = SM + 16384 + cur * 8192;

        // issue global prefetch for tile kt+1 (completes under compute)
        if (kt + 1 < NKT) {
            const bf16* src = kS + (size_t)(kt + 1) * KVT * CDIM;
            #pragma unroll
            for (int u = 0; u < 4; ++u) {
                kreg[u] = *reinterpret_cast<const short8v*>(src + (size_t)krow * CDIM + (kch + 8 * u) * 8);
                vreg[u] = *reinterpret_cast<const short8v*>(vtS + (size_t)tid * HW + (kt + 1) * KVT + u * 8);
            }
        }

        // ---- QK^T on current buffer ----
        f32x4 sa[2];
        sa[0] = (f32x4){0.f, 0.f, 0.f, 0.f};
        sa[1] = (f32x4){0.f, 0.f, 0.f, 0.f};
        __builtin_amdgcn_s_setprio(1);
        #pragma unroll
        for (int ks = 0; ks < 8; ++ks) {
            #pragma unroll
            for (int cf = 0; cf < 2; ++cf) {
                const int row = cf * 16 + lo16;
                short8v bfr = *reinterpret_cast<const short8v*>(
                    &Kc[row * 256 + ((4 * ks + hi4) ^ (lo16 & 7)) * 8]);
                sa[cf] = __builtin_amdgcn_mfma_f32_16x16x32_bf16(qf[ks], bfr, sa[cf], 0, 0, 0);
            }
        }
        __builtin_amdgcn_s_setprio(0);

        // ---- P = exp(S); lane-local l partials; P -> LDS swizzled ----
        #pragma unroll
        for (int cf = 0; cf < 2; ++cf)
            #pragma unroll
            for (int g = 0; g < 4; ++g) {
                const float e = __expf(sa[cf][g]);
                lp[g] += e;
                bf16 hb = __float2bfloat16(e);
                const int r = 4 * hi4 + g;
                const int ch = (2 * cf + (lo16 >> 3)) ^ ((r >> 1) & 3);
                SM[32768 + wave * 512 + r * 32 + ch * 8 + (lo16 & 7)] = *reinterpret_cast<short*>(&hb);
            }

        const short8v pa = *reinterpret_cast<const short8v*>(&SM[32768 + wave * 512 + pvRow]);

        // ---- PV on current buffer ----
        __builtin_amdgcn_s_setprio(1);
        #pragma unroll
        for (int cf = 0; cf < 16; ++cf) {
            const int row = cf * 16 + lo16;
            const short8v vb = *reinterpret_cast<const short8v*>(
                &Vc[row * 32 + (hi4 ^ ((lo16 >> 1) & 3)) * 8]);
            Oacc[cf] = __builtin_amdgcn_mfma_f32_16x16x32_bf16(pa, vb, Oacc[cf], 0, 0, 0);
        }
        __builtin_amdgcn_s_setprio(0);

        // ---- publish tile kt+1 into the idle buffer (safe: readers of it
        //      finished before the barrier that ended iter kt-1) ----
        if (kt + 1 < NKT) {
            short* Kn = SM + nxt * 8192;
            short* Vn = SM + 16384 + nxt * 8192;
            #pragma unroll
            for (int u = 0; u < 4; ++u)
                *reinterpret_cast<short8v*>(&Kn[krow * 256 + ((kch ^ kxor) + 8 * u) * 8]) = kreg[u];
            #pragma unroll
            for (int u = 0; u < 4; ++u)
                *reinterpret_cast<short8v*>(&Vn[tid * 32 + (u ^ vxor) * 8]) = vreg[u];
        }
        __syncthreads();   // single barrier per tile
    }

    // ---- epilogue ----
    float inv[4];
    #pragma unroll
    for (int g = 0; g < 4; ++g) {
        float l = lp[g];
        #pragma unroll
        for (int off = 1; off < 16; off <<= 1) l += __shfl_xor(l, off);
        inv[g] = 1.0f / l;
    }
    const float* imgS = img + (size_t)s * CDIM * HW;
    float*       outS = out + (size_t)s * CDIM * HW;
    const int tt = t0 + wave * 16 + 4 * hi4;
    #pragma unroll
    for (int cf = 0; cf < 16; ++cf) {
        const int c = cf * 16 + lo16;
        const float4 r4 = *reinterpret_cast<const float4*>(imgS + (size_t)c * HW + tt);
        float4 o;
        o.x = Oacc[cf][0] * inv[0] + r4.x;
        o.y = Oacc[cf][1] * inv[1] + r4.y;
        o.z = Oacc[cf][2] * inv[2] + r4.z;
        o.w = Oacc[cf][3] * inv[3] + r4.w;
        *reinterpret_cast<float4*>(outS + (size_t)c * HW + tt) = o;
    }
}

// ---------------------------------------------------------------------------
extern "C" void kernel_launch(void* const* d_in, const int* in_sizes, int n_in,
                              void* d_out, int out_size, void* d_ws, size_t ws_size,
                              hipStream_t stream)
{
    const float* img = (const float*)d_in[0];
    const float* dep = (const float*)d_in[1];
    const float* Wq  = (const float*)d_in[2];
    const float* bq  = (const float*)d_in[3];
    const float* Wk  = (const float*)d_in[4];
    const float* bk  = (const float*)d_in[5];
    const float* Wv  = (const float*)d_in[6];
    const float* bv  = (const float*)d_in[7];
    float* out = (float*)d_out;

    const size_t npt  = (size_t)NSLICE * HW * CDIM;
    const size_t need = 3 * npt * sizeof(bf16) + 3 * 65536 * sizeof(bf16);
    if (ws_size < need) {
        hipMemsetAsync(d_out, 0, (size_t)out_size * sizeof(float), stream);
        return;
    }

    bf16* q  = (bf16*)d_ws;        // token-major, prescaled
    bf16* k  = q + npt;            // token-major
    bf16* vt = k + npt;            // channel-major
    bf16* wt = vt + npt;           // [3][256][256] W^T

    // allow >64KB dynamic LDS for the flash kernel (idempotent, host-side)
    hipFuncSetAttribute((const void*)flash_mfma_kernel,
                        hipFuncAttributeMaxDynamicSharedMemorySize,
                        FLASH_LDS_BYTES);

    wt_prep_kernel<<<dim3(3 * 256), 256, 0, stream>>>(Wq, Wk, Wv, wt);

    proj_q_kernel<<<dim3(NSLICE * 32), 256, 0, stream>>>(img, wt, bq, q);
    proj_kv_kernel<<<dim3(NSLICE * 32), 256, 0, stream>>>(dep, wt, bk, bv, k, vt);

    flash_mfma_kernel<<<dim3(NSLICE * 16), 256, FLASH_LDS_BYTES, stream>>>(
        q, k, vt, img, out);
}